// Round 1
// 174.867 us; speedup vs baseline: 1.0064x; 1.0064x over previous
//
#include <hip/hip_runtime.h>

// BERT lattice embedding: ragged segment mean-pool.
// hidden: [B,S,H] f32, word_ids: [B,S] i32 (non-decreasing per sample),
// out: [B,T,H] f32 with out[b,t,:] = mean of hidden[b,s,:] over s where
// word_ids[b,s]==t (zeros if no such s).
//
// v2: latency/occupancy fix.
//  - 256-thread blocks, 4 consecutive output rows (same b; T=400 % 4 == 0),
//    one wave (64 lanes) per row. 4-wave workgroups lift occupancy from the
//    1-wave-block workgroup cap (~60%) toward 32 waves/CU.
//  - word_ids row (512 ints = 2 KB) is cooperatively staged in LDS once per
//    block; the two binary searches per row become LDS searches (9 cheap LDS
//    reads, shared across 4 rows) instead of ~18 serially-dependent global
//    loads per wave. end(t) == lower_bound(t+1), so 5 bounds serve 4 rows.
//  - Streaming part unchanged: lane i handles float4 indices {i, i+64, i+128}
//    of the 768-float row (768 = 192 float4 = 64 lanes x 3), fully coalesced.

#define BB 64
#define SS 512
#define HH 768
#define TT 400
#define RPB 4   // rows (words) per block; TT % RPB == 0

__global__ __launch_bounds__(256) void bert_lattice_pool_kernel(
    const float* __restrict__ hidden,
    const int* __restrict__ word_ids,
    float* __restrict__ out)
{
    const int row0 = blockIdx.x * RPB;  // b*TT + t0
    const int b    = row0 / TT;
    const int t0   = row0 - b * TT;

    __shared__ int s_w[SS];
    __shared__ int s_bounds[RPB + 1];

    // Stage the word_ids row: 512 ints = 256 int2, one per thread, coalesced.
    const int2* wrow2 = reinterpret_cast<const int2*>(word_ids + b * SS);
    reinterpret_cast<int2*>(s_w)[threadIdx.x] = wrow2[threadIdx.x];
    __syncthreads();

    // 5 threads compute lower_bound(t0 + i) for i = 0..4 in LDS.
    // start(t) = lower_bound(t), end(t) = lower_bound(t+1).
    if (threadIdx.x <= RPB) {
        const int t = t0 + threadIdx.x;
        int lo = 0, hi = SS;
        while (lo < hi) {
            int mid = (lo + hi) >> 1;
            if (s_w[mid] < t) lo = mid + 1; else hi = mid;
        }
        s_bounds[threadIdx.x] = lo;
    }
    __syncthreads();

    const int wv    = threadIdx.x >> 6;   // wave 0..3 -> row t0+wv
    const int lane  = threadIdx.x & 63;
    const int start = s_bounds[wv];
    const int end   = s_bounds[wv + 1];
    const int count = end - start;

    float4 acc0 = make_float4(0.f, 0.f, 0.f, 0.f);
    float4 acc1 = make_float4(0.f, 0.f, 0.f, 0.f);
    float4 acc2 = make_float4(0.f, 0.f, 0.f, 0.f);

    for (int s = start; s < end; ++s) {
        const float4* p =
            reinterpret_cast<const float4*>(hidden + ((size_t)b * SS + s) * HH);
        float4 v0 = p[lane];
        float4 v1 = p[lane + 64];
        float4 v2 = p[lane + 128];
        acc0.x += v0.x; acc0.y += v0.y; acc0.z += v0.z; acc0.w += v0.w;
        acc1.x += v1.x; acc1.y += v1.y; acc1.z += v1.z; acc1.w += v1.w;
        acc2.x += v2.x; acc2.y += v2.y; acc2.z += v2.z; acc2.w += v2.w;
    }

    const float inv = 1.0f / (float)(count > 0 ? count : 1);

    float4* o = reinterpret_cast<float4*>(out + ((size_t)(row0 + wv)) * HH);
    float4 r0 = make_float4(acc0.x * inv, acc0.y * inv, acc0.z * inv, acc0.w * inv);
    float4 r1 = make_float4(acc1.x * inv, acc1.y * inv, acc1.z * inv, acc1.w * inv);
    float4 r2 = make_float4(acc2.x * inv, acc2.y * inv, acc2.z * inv, acc2.w * inv);
    o[lane]       = r0;
    o[lane + 64]  = r1;
    o[lane + 128] = r2;
}

extern "C" void kernel_launch(void* const* d_in, const int* in_sizes, int n_in,
                              void* d_out, int out_size, void* d_ws, size_t ws_size,
                              hipStream_t stream) {
    (void)in_sizes; (void)n_in; (void)d_ws; (void)ws_size; (void)out_size;
    const float* hidden   = (const float*)d_in[0];
    const int*   word_ids = (const int*)d_in[1];
    float*       out      = (float*)d_out;

    // 4 output rows per 256-thread block.
    dim3 grid((BB * TT) / RPB);
    dim3 block(256);
    bert_lattice_pool_kernel<<<grid, block, 0, stream>>>(hidden, word_ids, out);
}